// Round 3
// baseline (483.248 us; speedup 1.0000x reference)
//
#include <hip/hip_runtime.h>
#include <math.h>

#define NN 102400
#define FD 128
#define KC 16
#define BG 64
#define NPG 1600
#define NE 3276800
#define HB 512           // level-1 hist/scatter blocks
#define EH (NE / HB)     // 6400 edges per block
// u32s zeroed by k_s: adj(16384) cc(16384) outx(131072) scal(8) done(8) M(1638400)
#define ZTOT (16384 + 16384 + 131072 + 8 + 8 + 1638400)

__device__ __forceinline__ void glob_addf(float* p, float v) {
  unsafeAtomicAdd(p, v);
}
__device__ __forceinline__ unsigned f2bf(float f) {
  unsigned u = __float_as_uint(f);
  u += 0x7FFFu + ((u >> 16) & 1u);
  return (u >> 16) & 0xFFFFu;
}
__device__ __forceinline__ float bf2f(unsigned h) {
  return __uint_as_float(h << 16);
}

// -------------------- k_s: softmax^2(x@W+b) + zero accumulators --------------------
__global__ __launch_bounds__(256) void k_s(const float* __restrict__ x,
    const float* __restrict__ W, const float* __restrict__ bb,
    float* __restrict__ s, unsigned* __restrict__ zbase) {
  const int t = threadIdx.x;
  const int n = blockIdx.x * 256 + t;
  for (int i = n; i < ZTOT; i += NN) zbase[i] = 0u;
  float acc[KC];
#pragma unroll
  for (int k = 0; k < KC; ++k) acc[k] = bb[k];
  const float4* xr = (const float4*)(x + (size_t)n * FD);
#pragma unroll 4
  for (int c = 0; c < FD / 4; ++c) {
    float4 v = xr[c];
    const float* wr = W + c * 4 * KC;   // wave-uniform -> scalar loads
#pragma unroll
    for (int k = 0; k < KC; ++k)
      acc[k] += v.x * wr[k] + v.y * wr[KC + k] + v.z * wr[2 * KC + k] + v.w * wr[3 * KC + k];
  }
#pragma unroll
  for (int r = 0; r < 2; ++r) {
    float m = acc[0];
#pragma unroll
    for (int k = 1; k < KC; ++k) m = fmaxf(m, acc[k]);
    float sum = 0.f;
#pragma unroll
    for (int k = 0; k < KC; ++k) { acc[k] = expf(acc[k] - m); sum += acc[k]; }
    float inv = 1.f / sum;
#pragma unroll
    for (int k = 0; k < KC; ++k) acc[k] *= inv;
  }
  float4* so = (float4*)(s + (size_t)n * KC);
  so[0] = make_float4(acc[0], acc[1], acc[2], acc[3]);
  so[1] = make_float4(acc[4], acc[5], acc[6], acc[7]);
  so[2] = make_float4(acc[8], acc[9], acc[10], acc[11]);
  so[3] = make_float4(acc[12], acc[13], acc[14], acc[15]);
}

// -------------------- level-1: per-(graph,block) histogram --------------------
__global__ __launch_bounds__(256) void k_hist(const int* __restrict__ esrc,
    unsigned* __restrict__ blkhist) {
  __shared__ unsigned h[BG];
  const int t = threadIdx.x, b = blockIdx.x;
  if (t < BG) h[t] = 0u;
  __syncthreads();
  const int e0 = b * EH;
  for (int i = t; i < EH; i += 256) {
    unsigned g = (unsigned)esrc[e0 + i] / (unsigned)NPG;
    atomicAdd(&h[g], 1u);           // ds_add, no-return
  }
  __syncthreads();
  if (t < BG) blkhist[t * HB + b] = h[t];
}

// -------------------- level-1 scan A (HB=512 entries per graph) --------------------
__global__ __launch_bounds__(512) void k_scan_a(unsigned* __restrict__ blkhist,
    unsigned* __restrict__ gtot) {
  __shared__ unsigned wsum[8];
  const int t = threadIdx.x, g = blockIdx.x;
  const int lane = t & 63;
  unsigned v = blkhist[g * HB + t];
  unsigned inc = v;
#pragma unroll
  for (int o = 1; o < 64; o <<= 1) {
    unsigned nb = __shfl_up(inc, o, 64);
    if (lane >= o) inc += nb;
  }
  if (lane == 63) wsum[t >> 6] = inc;
  __syncthreads();
  if (t == 0) {
    unsigned run = 0;
#pragma unroll
    for (int i = 0; i < 8; ++i) { unsigned c = wsum[i]; wsum[i] = run; run += c; }
    gtot[g] = run;
  }
  __syncthreads();
  blkhist[g * HB + t] = inc - v + wsum[t >> 6];
}

// -------------------- level-1 scan B --------------------
__global__ void k_scan_b(const unsigned* __restrict__ gtot, unsigned* __restrict__ gbase) {
  if (threadIdx.x == 0) {
    unsigned run = 0;
    for (int g = 0; g < BG; ++g) { gbase[g] = run; run += gtot[g]; }
    gbase[BG] = run;   // == NE
  }
}

// -------------------- level-1 scatter: sort by graph (write-local) --------------------
__global__ __launch_bounds__(256) void k_scatter1(const float* __restrict__ ew,
    const int* __restrict__ esrc, const int* __restrict__ edst,
    const unsigned* __restrict__ blkhist, const unsigned* __restrict__ gbase,
    unsigned short* __restrict__ skey, unsigned* __restrict__ pay) {
  __shared__ unsigned h[BG];
  __shared__ unsigned off[BG];
  const int t = threadIdx.x, b = blockIdx.x;
  if (t < BG) { h[t] = 0u; off[t] = gbase[t] + blkhist[t * HB + b]; }
  __syncthreads();
  const int e0 = b * EH;
  for (int i = t; i < EH; i += 256) {
    int e = e0 + i;
    int s0 = esrc[e], d0 = edst[e];
    float w = ew[e];
    unsigned g = (unsigned)s0 / (unsigned)NPG;
    unsigned r = atomicAdd(&h[g], 1u);
    unsigned pos = off[g] + r;
    skey[pos] = (unsigned short)((unsigned)s0 - g * NPG);
    pay[pos] = (((unsigned)d0 - g * NPG) << 16) | f2bf(w);
  }
}

// ---- k_msc: M[i,:] = sum_{e:src=i} w*s[dst,:] via LDS atomics; den folded ----
// Block (g,h): h-th quarter of the 16 columns, Ml[1600][4] in LDS (25.6KB).
// No ordering needed within the graph -> level-2 sort eliminated entirely.
__global__ __launch_bounds__(512) void k_msc(const float* __restrict__ s,
    const unsigned short* __restrict__ skey, const unsigned* __restrict__ pay,
    const unsigned* __restrict__ gbase, float* __restrict__ Mg,
    float* __restrict__ den) {
  __shared__ float Ml[NPG * 4];
  __shared__ float scr[8];
  const int t = threadIdx.x;
  const int g = blockIdx.x & 63;        // same-XCD for all 4 quarters of a graph
  const int h = blockIdx.x >> 6;        // 0..3 column quarter
  const int ll = t & 3;
  const int grp = t >> 2;               // 0..127
  for (int i = t; i < NPG * 4; i += 512) Ml[i] = 0.f;
  __syncthreads();
  const unsigned gb = gbase[g], ge = gbase[g + 1];
  const float* sG = s + (size_t)g * NPG * KC + h * 4 + ll;  // pre-offset column
  float dacc = 0.f;
  unsigned e = gb + grp;
  for (; e + 384 < ge; e += 512) {      // 4 independent edges in flight per lane
    unsigned pk0 = pay[e],       pk1 = pay[e + 128];
    unsigned pk2 = pay[e + 256], pk3 = pay[e + 384];
    unsigned sk0 = skey[e],       sk1 = skey[e + 128];
    unsigned sk2 = skey[e + 256], sk3 = skey[e + 384];
    float sv0 = sG[(pk0 >> 16) * KC];
    float sv1 = sG[(pk1 >> 16) * KC];
    float sv2 = sG[(pk2 >> 16) * KC];
    float sv3 = sG[(pk3 >> 16) * KC];
    float t0 = bf2f(pk0 & 0xFFFFu) * sv0;
    float t1 = bf2f(pk1 & 0xFFFFu) * sv1;
    float t2 = bf2f(pk2 & 0xFFFFu) * sv2;
    float t3 = bf2f(pk3 & 0xFFFFu) * sv3;
    dacc = fmaf(t0, sv0, dacc);
    dacc = fmaf(t1, sv1, dacc);
    dacc = fmaf(t2, sv2, dacc);
    dacc = fmaf(t3, sv3, dacc);
    atomicAdd(&Ml[sk0 * 4 + ll], t0);   // ds_add_f32, no-return
    atomicAdd(&Ml[sk1 * 4 + ll], t1);
    atomicAdd(&Ml[sk2 * 4 + ll], t2);
    atomicAdd(&Ml[sk3 * 4 + ll], t3);
  }
  for (; e < ge; e += 128) {
    unsigned pk0 = pay[e];
    unsigned sk0 = skey[e];
    float sv0 = sG[(pk0 >> 16) * KC];
    float t0 = bf2f(pk0 & 0xFFFFu) * sv0;
    dacc = fmaf(t0, sv0, dacc);
    atomicAdd(&Ml[sk0 * 4 + ll], t0);
  }
  __syncthreads();
  // write out this block's column quarter; same-XCD partial lines merge in L2
  float* Mo = Mg + (size_t)g * NPG * KC + h * 4;
  for (int i = t; i < NPG; i += 512) {
    float4 v = *(const float4*)&Ml[i * 4];
    *(float4*)&Mo[(size_t)i * KC] = v;
  }
#pragma unroll
  for (int o = 32; o > 0; o >>= 1) dacc += __shfl_down(dacc, o, 64);
  if ((t & 63) == 0) scr[t >> 6] = dacc;
  __syncthreads();
  if (t == 0) {
    float sum = 0.f;
#pragma unroll
    for (int i = 0; i < 8; ++i) sum += scr[i];
    glob_addf(den, sum);
  }
}

// ---- k_mid: CC = S^T S, out_x = S^T X, out_adj = S^T M (fused dense contraction) ----
__global__ __launch_bounds__(256, 8) void k_mid(const float* __restrict__ s,
    const float* __restrict__ x, const float* __restrict__ Mg,
    float* __restrict__ cc_raw, float* __restrict__ outx_raw,
    float* __restrict__ adj_raw) {
  __shared__ float st[100 * KC];
  __shared__ float mt[100 * KC];
  const int t = threadIdx.x;
  const int g = blockIdx.x >> 4, sub = blockIdx.x & 15;
  const int n0 = g * NPG + sub * 100;
  const int j = t & 127, h = t >> 7;
  const int kc = t >> 4, lc = t & 15;
  for (int u = t; u < 100 * KC; u += 256) {
    st[u] = s[(size_t)n0 * KC + u];
    mt[u] = Mg[(size_t)n0 * KC + u];
  }
  __syncthreads();
  float accX[8] = {0.f, 0.f, 0.f, 0.f, 0.f, 0.f, 0.f, 0.f};
  float accC = 0.f, accA = 0.f;
  for (int i = 0; i < 100; ++i) {
    const float xv = x[(size_t)(n0 + i) * FD + j];
    const float* si = st + i * KC;
#pragma unroll
    for (int kk = 0; kk < 8; ++kk) accX[kk] = fmaf(si[h * 8 + kk], xv, accX[kk]);
    accC = fmaf(si[kc], si[lc], accC);
    accA = fmaf(si[kc], mt[i * KC + lc], accA);
  }
#pragma unroll
  for (int kk = 0; kk < 8; ++kk)
    glob_addf(outx_raw + g * 2048 + (h * 8 + kk) * 128 + j, accX[kk]);
  glob_addf(cc_raw + g * 256 + t, accC);
  glob_addf(adj_raw + g * 256 + t, accA);
}

// -------------------- k_post: normalize adj, trace, ortho, SELU --------------------
__device__ __forceinline__ float bred(float v, float* scr) {
#pragma unroll
  for (int o = 32; o > 0; o >>= 1) v += __shfl_down(v, o, 64);
  __syncthreads();
  if ((threadIdx.x & 63) == 0) scr[threadIdx.x >> 6] = v;
  __syncthreads();
  return scr[0] + scr[1] + scr[2] + scr[3];
}

__global__ __launch_bounds__(256) void k_post(const float* __restrict__ adj_raw,
    const float* __restrict__ cc_raw, const float* __restrict__ outx_raw,
    float* __restrict__ out, float* __restrict__ scal, unsigned* __restrict__ done) {
  const int b = blockIdx.x, t = threadIdx.x;
  const int k = t >> 4, l = t & 15;
  __shared__ float m[16 * 17];
  __shared__ float dk[16];
  __shared__ float scr[4];
  const float raw = adj_raw[b * 256 + t];
  const float masked = (k == l) ? 0.f : raw;
  m[k * 17 + l] = masked;
  __syncthreads();
  if (t < 16) {
    float rs = 0.f;
#pragma unroll
    for (int ll = 0; ll < 16; ++ll) rs += m[t * 17 + ll];
    dk[t] = sqrtf(rs) + 1e-12f;
  }
  __syncthreads();
  out[131072 + b * 256 + t] = masked / (dk[k] * dk[l]);
  float tr = bred((k == l) ? raw : 0.f, scr);
  if (t == 0) glob_addf(scal + 1, tr);
  const float c = cc_raw[b * 256 + t];
  float n2 = bred(c * c, scr);
  float diff = c / sqrtf(n2) - ((k == l) ? 0.25f : 0.f);
  float d2 = bred(diff * diff, scr);
  if (t == 0) glob_addf(scal + 2, sqrtf(d2));
  for (int idx = b * 256 + t; idx < 131072; idx += 16384) {
    float xv = outx_raw[idx];
    out[idx] = xv > 0.f ? 1.0507009873554805f * xv
                        : 1.0507009873554805f * 1.6732632423543772f * expm1f(xv);
  }
  __syncthreads();
  if (t == 0) {
    __threadfence();
    unsigned v = __hip_atomic_fetch_add(done, 1u, __ATOMIC_ACQ_REL,
                                        __HIP_MEMORY_SCOPE_AGENT);
    if (v == 63u) {   // last block: all contributions visible
      float den   = __hip_atomic_load(scal + 0, __ATOMIC_RELAXED, __HIP_MEMORY_SCOPE_AGENT);
      float num   = __hip_atomic_load(scal + 1, __ATOMIC_RELAXED, __HIP_MEMORY_SCOPE_AGENT);
      float ortho = __hip_atomic_load(scal + 2, __ATOMIC_RELAXED, __HIP_MEMORY_SCOPE_AGENT);
      out[147456] = -num / den;
      out[147457] = ortho * (1.f / 64.f);
    }
  }
}

// -------------------- launch --------------------
extern "C" void kernel_launch(void* const* d_in, const int* in_sizes, int n_in,
                              void* d_out, int out_size, void* d_ws, size_t ws_size,
                              hipStream_t stream) {
  const float* x  = (const float*)d_in[0];
  const float* W  = (const float*)d_in[1];
  const float* bb = (const float*)d_in[2];
  const float* ew = (const float*)d_in[3];
  const int* esrc = (const int*)d_in[4];
  const int* edst = (const int*)d_in[5];
  float* out = (float*)d_out;
  float* ws = (float*)d_ws;

  float* s_buf   = ws;                                    // 1,638,400 f
  float* adj_raw = s_buf + (size_t)NN * KC;               // 16,384 f   <- zero region start
  float* cc_raw  = adj_raw + 16384;                       // 16,384 f
  float* outx    = cc_raw + 16384;                        // 131,072 f
  float* scal    = outx + 131072;                         // 8 f: [0]=den [1]=num [2]=ortho
  unsigned* done = (unsigned*)(scal + 8);                 // 8 u
  float* Mg      = (float*)(done + 8);                    // 1,638,400 f <- zero region end
  unsigned* blkhist = (unsigned*)(Mg + (size_t)NN * KC);  // 64*512 u
  unsigned* gtot    = blkhist + (size_t)BG * HB;          // 64 u
  unsigned* gbase   = gtot + BG;                          // 72 u (65 used)
  unsigned short* skey = (unsigned short*)(gbase + 72);   // NE u16 (src keys)
  unsigned* pay = (unsigned*)(skey + NE);                 // NE u32 (dst<<16 | bf16 w)
  // total ~= 33.56 MB (< 33.69 MB proven available)

  k_s<<<NN / 256, 256, 0, stream>>>(x, W, bb, s_buf, (unsigned*)adj_raw);
  k_hist<<<HB, 256, 0, stream>>>(esrc, blkhist);
  k_scan_a<<<BG, 512, 0, stream>>>(blkhist, gtot);
  k_scan_b<<<1, 64, 0, stream>>>(gtot, gbase);
  k_scatter1<<<HB, 256, 0, stream>>>(ew, esrc, edst, blkhist, gbase, skey, pay);
  k_msc<<<BG * 4, 512, 0, stream>>>(s_buf, skey, pay, gbase, Mg, scal);
  k_mid<<<BG * 16, 256, 0, stream>>>(s_buf, x, Mg, cc_raw, outx, adj_raw);
  k_post<<<64, 256, 0, stream>>>(adj_raw, cc_raw, outx, out, scal, done);
}